// Round 1
// baseline (16772.614 us; speedup 1.0000x reference)
//
#include <hip/hip_runtime.h>
#include <hip/hip_fp16.h>

#define B_ 128
#define T_ 512
#define E_ 128
#define D_ 128

// exp2(C2*x) == e^(2x);  L2E = log2(e)
#define C2f 2.885390081777927f
#define L2E 1.4426950408889634f

__device__ __forceinline__ float rcpf_(float x){ return __builtin_amdgcn_rcpf(x); }
__device__ __forceinline__ float ex2_(float x){ return __builtin_amdgcn_exp2f(x); }

// device-scope (cross-XCD coherent) data/flag helpers
__device__ __forceinline__ void gstoref(float* p, float v){
    __hip_atomic_store(p, v, __ATOMIC_RELAXED, __HIP_MEMORY_SCOPE_AGENT);
}
__device__ __forceinline__ float gloadf(const float* p){
    return __hip_atomic_load(p, __ATOMIC_RELAXED, __HIP_MEMORY_SCOPE_AGENT);
}
__device__ __forceinline__ void flag_set(int* p, int v){
    __hip_atomic_store(p, v, __ATOMIC_RELEASE, __HIP_MEMORY_SCOPE_AGENT);
}
__device__ __forceinline__ void flag_wait(int* p, int v){
    int it = 0;
    while (__hip_atomic_load(p, __ATOMIC_ACQUIRE, __HIP_MEMORY_SCOPE_AGENT) < v
           && it < (1 << 26)){ it++; __builtin_amdgcn_s_sleep(2); }
}

// out[n][k] = (half) in[k][n],  K x N input, 32x32 tiles, 256 threads.
__global__ __launch_bounds__(256) void transpose_half(const float* __restrict__ in,
                                                      __half* __restrict__ out,
                                                      int K, int N){
    __shared__ float tile[32][33];
    int n0 = blockIdx.x * 32, k0 = blockIdx.y * 32;
    int tx = threadIdx.x & 31, ty = threadIdx.x >> 5;
    #pragma unroll
    for (int i = ty; i < 32; i += 8)
        tile[i][tx] = in[(size_t)(k0 + i) * N + n0 + tx];
    __syncthreads();
    #pragma unroll
    for (int i = ty; i < 32; i += 8)
        out[(size_t)(n0 + i) * K + k0 + tx] = __float2half(tile[tx][i]);
}

// fp16 copy of enc (for phase C streaming)
__global__ __launch_bounds__(256) void enc_to_half(const float* __restrict__ in,
                                                   __half* __restrict__ out){
    int i = (blockIdx.x * 256 + threadIdx.x) * 4;
    float4 v = *(const float4*)(in + i);
    __half2 a = __floats2half2_rn(v.x, v.y);
    __half2 b = __floats2half2_rn(v.z, v.w);
    *(__half2*)(out + i)     = a;
    *(__half2*)(out + i + 2) = b;
}

// P[b][n][t] = exp2(C2 * (sum_e enc[b][t][e]*Ua[e][n] + bu[n]))  as fp16
__global__ __launch_bounds__(256) void uenc_kernel(const float* __restrict__ enc,
                                                   const float* __restrict__ Ua,
                                                   const float* __restrict__ bu,
                                                   __half* __restrict__ P){
    int b = blockIdx.z;
    int t0 = blockIdx.x * 64;
    int n0 = blockIdx.y * 64;
    int tt = threadIdx.x & 63;
    int ng = threadIdx.x >> 6;
    const float* erow = enc + ((size_t)b * T_ + (t0 + tt)) * E_;
    const float* uap  = Ua + n0 + ng * 16;
    float acc[16];
    #pragma unroll
    for (int i = 0; i < 16; i++) acc[i] = 0.f;
    #pragma unroll 2
    for (int e0 = 0; e0 < E_; e0 += 4){
        float4 av = *(const float4*)(erow + e0);
        #pragma unroll
        for (int ee = 0; ee < 4; ee++){
            float a = (ee==0)?av.x:(ee==1)?av.y:(ee==2)?av.z:av.w;
            const float4* u4 = (const float4*)(uap + (size_t)(e0+ee) * T_);
            float4 x0 = u4[0], x1 = u4[1], x2 = u4[2], x3 = u4[3];
            acc[0]  = fmaf(a, x0.x, acc[0]);  acc[1]  = fmaf(a, x0.y, acc[1]);
            acc[2]  = fmaf(a, x0.z, acc[2]);  acc[3]  = fmaf(a, x0.w, acc[3]);
            acc[4]  = fmaf(a, x1.x, acc[4]);  acc[5]  = fmaf(a, x1.y, acc[5]);
            acc[6]  = fmaf(a, x1.z, acc[6]);  acc[7]  = fmaf(a, x1.w, acc[7]);
            acc[8]  = fmaf(a, x2.x, acc[8]);  acc[9]  = fmaf(a, x2.y, acc[9]);
            acc[10] = fmaf(a, x2.z, acc[10]); acc[11] = fmaf(a, x2.w, acc[11]);
            acc[12] = fmaf(a, x3.x, acc[12]); acc[13] = fmaf(a, x3.y, acc[13]);
            acc[14] = fmaf(a, x3.z, acc[14]); acc[15] = fmaf(a, x3.w, acc[15]);
        }
    }
    int nb = n0 + ng * 16;
    #pragma unroll
    for (int i = 0; i < 16; i++){
        float u = acc[i] + bu[nb + i];
        P[(size_t)b * T_ * T_ + (size_t)(nb + i) * T_ + t0 + tt] = __float2half(ex2_(C2f * u));
    }
}

__device__ __forceinline__ void dot8(float& acc, uint4 wv, float4 ha, float4 hb){
    float2 f0 = __half22float2(*reinterpret_cast<__half2*>(&wv.x));
    float2 f1 = __half22float2(*reinterpret_cast<__half2*>(&wv.y));
    float2 f2 = __half22float2(*reinterpret_cast<__half2*>(&wv.z));
    float2 f3 = __half22float2(*reinterpret_cast<__half2*>(&wv.w));
    acc = fmaf(ha.x, f0.x, acc); acc = fmaf(ha.y, f0.y, acc);
    acc = fmaf(ha.z, f1.x, acc); acc = fmaf(ha.w, f1.y, acc);
    acc = fmaf(hb.x, f2.x, acc); acc = fmaf(hb.y, f2.y, acc);
    acc = fmaf(hb.z, f3.x, acc); acc = fmaf(hb.w, f3.y, acc);
}

// 8 score-terms for one n-row: a_k += (-2Va[n]) / (P[n][t_k]*Q[n] + 1)
__device__ __forceinline__ void acc8(uint4 pv, float2 qv,
    float& a0, float& a1, float& a2, float& a3,
    float& a4, float& a5, float& a6, float& a7)
{
    float2 f0 = __half22float2(*reinterpret_cast<__half2*>(&pv.x));
    float2 f1 = __half22float2(*reinterpret_cast<__half2*>(&pv.y));
    float2 f2 = __half22float2(*reinterpret_cast<__half2*>(&pv.z));
    float2 f3 = __half22float2(*reinterpret_cast<__half2*>(&pv.w));
    float m;
    m = fmaf(f0.x, qv.x, 1.f); a0 = fmaf(rcpf_(m), qv.y, a0);
    m = fmaf(f0.y, qv.x, 1.f); a1 = fmaf(rcpf_(m), qv.y, a1);
    m = fmaf(f1.x, qv.x, 1.f); a2 = fmaf(rcpf_(m), qv.y, a2);
    m = fmaf(f1.y, qv.x, 1.f); a3 = fmaf(rcpf_(m), qv.y, a3);
    m = fmaf(f2.x, qv.x, 1.f); a4 = fmaf(rcpf_(m), qv.y, a4);
    m = fmaf(f2.y, qv.x, 1.f); a5 = fmaf(rcpf_(m), qv.y, a5);
    m = fmaf(f3.x, qv.x, 1.f); a6 = fmaf(rcpf_(m), qv.y, a6);
    m = fmaf(f3.y, qv.x, 1.f); a7 = fmaf(rcpf_(m), qv.y, a7);
}

// grid (128, 2): b = blockIdx.x, t-half id h = blockIdx.y. 1024 threads.
// t-split: each block produces scores/weights for its OWN 256 t-columns over
// ALL 512 n -> only ONE cross-block exchange per step (ctx partial + denom).
// LDS ~149 KB -> 1 block/CU -> all 256 blocks co-resident.
__global__ __launch_bounds__(1024) void decoder_kernel(
    const float* __restrict__ enc, const __half* __restrict__ enc_h, int use_f16,
    const float* __restrict__ labels,
    const float* __restrict__ init_h, const float* __restrict__ init_c,
    const float* __restrict__ Va,
    const float* __restrict__ ba, const float* __restrict__ bl,
    const float* __restrict__ Wc, const float* __restrict__ bc,
    const float* __restrict__ Wk,
    const float* __restrict__ W1, const float* __restrict__ b1,
    const float* __restrict__ W2, const float* __restrict__ b2,
    const __half* __restrict__ Wa_t, const __half* __restrict__ Wr_t,
    const __half* __restrict__ Pw,
    float* __restrict__ ctxbuf, int* __restrict__ fA,
    float* __restrict__ out)
{
    __shared__ __align__(16) __half Plds[224 * 256];  // 112 KB: 224 n-rows x own t-half
    __shared__ __align__(16) float hc_s[256];         // h [0,128), c [128,256)
    __shared__ __align__(16) float ctx_s[128];
    __shared__ __align__(16) float2 QV[512];          // .x = Q[n]=e^{2s}, .y = -2*Va[n]
    __shared__ __align__(16) float sc[256];           // p[t] (own t-half, unnormalized)
    __shared__ __align__(16) float rz[512];           // h@Wr + bl
    __shared__ __align__(16) float scratch[4096];     // 16 KB partials (B and C reuse)
    __shared__ __align__(16) float ba_s[512], bl_s[512], Wk_s[512], lab_s[512];
    __shared__ float Wc_s[132];
    __shared__ float red[20];

    const int tid = threadIdx.x;
    const int b = blockIdx.x;
    const int h_ = blockIdx.y;          // t-half id

    if (tid < 128){
        hc_s[tid]       = init_h[b*128 + tid];
        hc_s[128 + tid] = init_c[b*128 + tid];
    }
    if (tid < 512){
        QV[tid].y = -2.f * Va[tid];
        ba_s[tid] = ba[tid];
        bl_s[tid] = bl[tid];
        Wk_s[tid] = Wk[tid];
        lab_s[tid] = labels[(size_t)b * T_ + tid];
    }
    if (tid < 129) Wc_s[tid] = Wc[tid];
    if (tid == 129) Wc_s[130] = bc[0];

    // block's t-half columns of P[b]: t in [256h, 256h+256)
    const __half* Pb  = Pw + (size_t)b * T_ * T_ + 256 * h_;
    const uint4*  Pb4 = (const uint4*)Pb;        // row n at +n*64 uint4, col-chunk +q

    // LDS fill: lds row r = 7g + j  <->  global row n = 16g + j (j < 7)
    {
        int lane = tid & 31, row = tid >> 5;
        #pragma unroll
        for (int r = row; r < 224; r += 32){
            int gg = r / 7, jj = r - 7 * gg;
            ((uint4*)Plds)[r * 32 + lane] = Pb4[(size_t)(16*gg + jj) * 64 + lane];
        }
    }
    __syncthreads();

    int* myf = &fA[b*2 + h_];
    int* pf  = &fA[b*2 + (1 - h_)];

    const int q   = tid & 31;   // t-chunk (8 halfs) within own half
    const int g   = tid >> 5;   // n-group (16 rows)
    const int wid = tid >> 6;   // wave id

    for (int t = 0; t < T_; t++){
        const int par = t & 1;
        float* cxme = ctxbuf + ((size_t)par * 256 + b*2 + h_)      * 132;
        float* cxpr = ctxbuf + ((size_t)par * 256 + b*2 + (1-h_))  * 132;

        // ---- prefetch phase-B global P rows (j = 7..15) into registers;
        //      latency hides under phase A
        uint4 gv0,gv1,gv2,gv3,gv4,gv5,gv6,gv7,gv8;
        {
            const uint4* Pg = Pb4 + (size_t)(16*g + 7) * 64 + q;
            gv0 = Pg[0*64]; gv1 = Pg[1*64]; gv2 = Pg[2*64];
            gv3 = Pg[3*64]; gv4 = Pg[4*64]; gv5 = Pg[5*64];
            gv6 = Pg[6*64]; gv7 = Pg[7*64]; gv8 = Pg[8*64];
        }

        // ---- phase A: Q[n] = e^{2 s[n]} for ALL n (threads 0..511, full-k dot)
        if (tid < 512){
            const float4* hc4 = (const float4*)hc_s;
            const uint4* wa = (const uint4*)(Wa_t + (size_t)tid * 256);
            float ac0 = ba_s[tid], ac1 = 0.f, ac2 = 0.f, ac3 = 0.f;
            #pragma unroll 2
            for (int i = 0; i < 32; i += 4){
                uint4 w0 = wa[i], w1 = wa[i+1], w2 = wa[i+2], w3 = wa[i+3];
                dot8(ac0, w0, hc4[2*i],   hc4[2*i+1]);
                dot8(ac1, w1, hc4[2*i+2], hc4[2*i+3]);
                dot8(ac2, w2, hc4[2*i+4], hc4[2*i+5]);
                dot8(ac3, w3, hc4[2*i+6], hc4[2*i+7]);
            }
            QV[tid].x = ex2_(C2f * ((ac0 + ac1) + (ac2 + ac3)));
        }
        __syncthreads();

        // ---- phase B: own-t-half scores over all 512 n (7 LDS + 9 prefetched rows)
        {
            float a0=0.f,a1=0.f,a2=0.f,a3=0.f,a4=0.f,a5=0.f,a6=0.f,a7=0.f;
            const uint4* Pl = (const uint4*)Plds + (size_t)(7*g) * 32 + q;
            #pragma unroll
            for (int j = 0; j < 7; j++){
                uint4 pv = Pl[j * 32];
                acc8(pv, QV[16*g + j], a0,a1,a2,a3,a4,a5,a6,a7);
            }
            acc8(gv0, QV[16*g +  7], a0,a1,a2,a3,a4,a5,a6,a7);
            acc8(gv1, QV[16*g +  8], a0,a1,a2,a3,a4,a5,a6,a7);
            acc8(gv2, QV[16*g +  9], a0,a1,a2,a3,a4,a5,a6,a7);
            acc8(gv3, QV[16*g + 10], a0,a1,a2,a3,a4,a5,a6,a7);
            acc8(gv4, QV[16*g + 11], a0,a1,a2,a3,a4,a5,a6,a7);
            acc8(gv5, QV[16*g + 12], a0,a1,a2,a3,a4,a5,a6,a7);
            acc8(gv6, QV[16*g + 13], a0,a1,a2,a3,a4,a5,a6,a7);
            acc8(gv7, QV[16*g + 14], a0,a1,a2,a3,a4,a5,a6,a7);
            acc8(gv8, QV[16*g + 15], a0,a1,a2,a3,a4,a5,a6,a7);
            // reduce across the two n-groups within this wave
            a0 += __shfl_xor(a0, 32); a1 += __shfl_xor(a1, 32);
            a2 += __shfl_xor(a2, 32); a3 += __shfl_xor(a3, 32);
            a4 += __shfl_xor(a4, 32); a5 += __shfl_xor(a5, 32);
            a6 += __shfl_xor(a6, 32); a7 += __shfl_xor(a7, 32);
            if ((tid & 32) == 0){
                float4* o = (float4*)(scratch + wid*256 + q*8);
                o[0] = make_float4(a0,a1,a2,a3);
                o[1] = make_float4(a4,a5,a6,a7);
            }
        }
        __syncthreads();
        // ---- B-reduce: score -> unnormalized p; denominator partials
        if (tid < 256){
            float v = 0.f;
            #pragma unroll
            for (int ww = 0; ww < 16; ww++) v += scratch[ww*256 + tid];
            float p = ex2_(v * L2E);
            sc[tid] = p;
            float ss = p;
            #pragma unroll
            for (int off = 32; off; off >>= 1) ss += __shfl_xor(ss, off);
            if ((tid & 63) == 0) red[tid >> 6] = ss;
        }
        __syncthreads();

        // ---- phase C: ctx partials over OWN t-half (unnormalized weights)
        {
            int eq = tid & 31, tg = tid >> 5;
            int trow = 256*h_ + tg*8;
            float4 acc = make_float4(0.f,0.f,0.f,0.f);
            if (use_f16){
                const uint2* ep = (const uint2*)(enc_h + ((size_t)b*T_ + trow)*E_) + eq;
                #pragma unroll
                for (int i = 0; i < 8; i++){
                    float wt = sc[tg*8 + i];
                    uint2 ev = ep[(size_t)i * 32];
                    float2 e01 = __half22float2(*reinterpret_cast<__half2*>(&ev.x));
                    float2 e23 = __half22float2(*reinterpret_cast<__half2*>(&ev.y));
                    acc.x = fmaf(wt, e01.x, acc.x); acc.y = fmaf(wt, e01.y, acc.y);
                    acc.z = fmaf(wt, e23.x, acc.z); acc.w = fmaf(wt, e23.y, acc.w);
                }
            } else {
                const float4* ep = (const float4*)(enc + ((size_t)b*T_ + trow)*E_) + eq;
                #pragma unroll
                for (int i = 0; i < 8; i++){
                    float wt = sc[tg*8 + i];
                    float4 ev = ep[(size_t)i * 32];
                    acc.x = fmaf(wt, ev.x, acc.x); acc.y = fmaf(wt, ev.y, acc.y);
                    acc.z = fmaf(wt, ev.z, acc.z); acc.w = fmaf(wt, ev.w, acc.w);
                }
            }
            *(float4*)(scratch + tg*128 + eq*4) = acc;
        }
        __syncthreads();
        // ---- C-reduce + publish (ctx partial [128] + denom partial [1])
        if (tid < 128){
            float s = 0.f;
            #pragma unroll
            for (int tg = 0; tg < 32; tg++) s += scratch[tg*128 + tid];
            ctx_s[tid] = s;
            gstoref(&cxme[tid], s);
        } else if (tid == 128){
            gstoref(&cxme[128], red[0] + red[1] + red[2] + red[3]);
        }
        __syncthreads();
        // ---- single exchange; rz = h@Wr + bl computed INSIDE the wait window
        if (tid == 0) flag_set(myf, t + 1);
        if (tid >= 512){
            const float4* hc4 = (const float4*)hc_s;
            int m = tid - 512;
            const uint4* wr = (const uint4*)(Wr_t + (size_t)m * 128);
            float r0 = bl_s[m], r1 = 0.f;
            #pragma unroll 2
            for (int i = 0; i < 16; i += 2){
                uint4 w0 = wr[i], w1 = wr[i+1];
                dot8(r0, w0, hc4[2*i],   hc4[2*i+1]);
                dot8(r1, w1, hc4[2*i+2], hc4[2*i+3]);
            }
            rz[m] = r0 + r1;
        }
        if (tid == 0) flag_wait(pf, t + 1);
        __syncthreads();
        // ---- combine ctx + denom, y-dot
        if (tid < 128){
            float dn = red[0] + red[1] + red[2] + red[3] + gloadf(&cxpr[128]);
            float ctxv = (ctx_s[tid] + gloadf(&cxpr[tid])) * rcpf_(dn);
            ctx_s[tid] = ctxv;
            float yp = ctxv * Wc_s[1 + tid];
            #pragma unroll
            for (int off = 32; off; off >>= 1) yp += __shfl_xor(yp, off);
            if ((tid & 63) == 0) red[16 + (tid >> 6)] = yp;
        }
        __syncthreads();
        // ---- phase D: gates (Keras i,f,g,o), update h,c   (dup in both blocks)
        if (tid < 128){
            float y = fmaf(lab_s[t], Wc_s[0], red[16] + red[17] + Wc_s[130]);
            float zi = rz[tid]       + y * Wk_s[tid];
            float zf = rz[128 + tid] + y * Wk_s[128 + tid];
            float zg = rz[256 + tid] + y * Wk_s[256 + tid];
            float zo = rz[384 + tid] + y * Wk_s[384 + tid];
            float si = rcpf_(1.f + ex2_(-L2E * zi));
            float sf = rcpf_(1.f + ex2_(-L2E * zf));
            float so = rcpf_(1.f + ex2_(-L2E * zo));
            float tg_ = 1.f - 2.f * rcpf_(ex2_(C2f * zg) + 1.f);
            float cn = sf * hc_s[128 + tid] + si * tg_;
            float tc = 1.f - 2.f * rcpf_(ex2_(C2f * cn) + 1.f);
            hc_s[128 + tid] = cn;
            hc_s[tid] = so * tc;
        }
        __syncthreads();
    }

    // ---- epilogue: pred = ([h, ctx] @ W1 + b1) @ W2 + b2   (h_==0 writes)
    if (tid < 128){
        float acc = b1[tid];
        for (int k = 0; k < 128; k++) acc = fmaf(hc_s[k],  W1[k*128 + tid], acc);
        for (int k = 0; k < 128; k++) acc = fmaf(ctx_s[k], W1[(128+k)*128 + tid], acc);
        scratch[tid] = acc * W2[tid];
    }
    __syncthreads();
    if (h_ == 0 && tid < 64){
        float a = scratch[tid] + scratch[64 + tid];
        #pragma unroll
        for (int off = 32; off; off >>= 1) a += __shfl_xor(a, off);
        if (tid == 0) out[b] = a + b2[0];
    }
}

extern "C" void kernel_launch(void* const* d_in, const int* in_sizes, int n_in,
                              void* d_out, int out_size, void* d_ws, size_t ws_size,
                              hipStream_t stream){
    const float* enc      = (const float*)d_in[0];
    const float* labels   = (const float*)d_in[1];
    const float* init_h   = (const float*)d_in[2];
    const float* init_c   = (const float*)d_in[3];
    const float* Wa = (const float*)d_in[5];
    const float* ba = (const float*)d_in[6];
    const float* Ua = (const float*)d_in[7];
    const float* bu = (const float*)d_in[8];
    const float* Va = (const float*)d_in[9];
    // d_in[10] = bv: softmax-shift-invariant, unused
    const float* Wc = (const float*)d_in[11];
    const float* bc = (const float*)d_in[12];
    const float* Wk = (const float*)d_in[13];
    const float* Wr = (const float*)d_in[14];
    const float* bl = (const float*)d_in[15];
    const float* W1 = (const float*)d_in[16];
    const float* b1 = (const float*)d_in[17];
    const float* W2 = (const float*)d_in[18];
    const float* b2 = (const float*)d_in[19];

    char* ws = (char*)d_ws;
    const size_t szP = (size_t)B_ * T_ * T_ * 2;       // 67,108,864
    const size_t szWa = 512 * 256 * 2;                 // 262,144
    const size_t szWr = 512 * 128 * 2;                 // 131,072
    const size_t base = szP + szWa + szWr;             // 67,502,080
    const size_t szEnc = (size_t)B_ * T_ * E_ * 2;     // 16,777,216
    const size_t commSz = (size_t)2*256*132*4 + 512*4; // 272,384

    __half* P    = (__half*)ws;
    __half* Wa_t = (__half*)(ws + szP);
    __half* Wr_t = (__half*)(ws + szP + szWa);

    int use_f16 = (ws_size >= base + szEnc + commSz) ? 1 : 0;
    __half* enc_h = (__half*)(ws + base);
    size_t comm0 = use_f16 ? (base + szEnc) : base;
    float* ctxbuf = (float*)(ws + comm0);
    int*   flags  = (int*)(ctxbuf + 2*256*132);

    hipMemsetAsync(flags, 0, 512 * sizeof(int), stream);

    transpose_half<<<dim3(16, 8, 1), 256, 0, stream>>>(Wa, Wa_t, 256, 512);
    transpose_half<<<dim3(16, 4, 1), 256, 0, stream>>>(Wr, Wr_t, 128, 512);
    if (use_f16)
        enc_to_half<<<8192, 256, 0, stream>>>(enc, enc_h);

    dim3 g1(T_/64, T_/64, B_);
    uenc_kernel<<<g1, 256, 0, stream>>>(enc, Ua, bu, P);

    decoder_kernel<<<dim3(B_, 2), 1024, 0, stream>>>(enc, enc_h, use_f16,
        labels, init_h, init_c, Va, ba, bl, Wc, bc, Wk, W1, b1, W2, b2,
        Wa_t, Wr_t, P, ctxbuf, flags, (float*)d_out);
}